// Round 12
// baseline (31.202 us; speedup 1.0000x reference)
//
#include <hip/hip_runtime.h>

// MEASUREMENT ROUND: exact round-4 kernels; gemm launched 3x (idempotent)
// to isolate gemm duration: dT vs 17.7us baseline = 2*(gemm_warm + launch).

// Problem constants
#define BATCH 2048
#define IN    512
#define OUT   512
#define NG    8
#define KTOT  1024   // concatenated K: [S | silu] x [Cw | w_b]

// GEMM tiling
#define BM 64
#define BN 64
#define BK 64
#define PAD 88                 // shorts per LDS row: 176B, 16B-aligned, <=2-way banks (free)
#define NIT (KTOT / BK)        // 16

typedef __attribute__((ext_vector_type(8))) short bf16x8;
typedef __attribute__((ext_vector_type(4))) float f32x4;

__device__ inline unsigned short f2bf(float f) {
    union { float f; unsigned int u; } v; v.f = f;
    unsigned int r = v.u + 0x7fffu + ((v.u >> 16) & 1u);
    return (unsigned short)(r >> 16);
}

// ---------------------------------------------------------------------------
// Fused prep: blocks [0,512) build A' (bf16), blocks [512,640) build B' (bf16)
//   A'[b][i] = sum_n exp(-(x[b,i]-g_n)^2)   A'[b][512+i] = silu(x[b,i])
//   B'[o][i] = (sum_a c[a,o,i]) * w_s[o,i]  B'[o][512+i] = w_b[o,i]
// Spline via uniform-grid factorization: 3 exp + Horner instead of 9 exp.
// ---------------------------------------------------------------------------
__global__ __launch_bounds__(256) void prep_kernel(const float* __restrict__ x,
                                                   const float* __restrict__ c,
                                                   const float* __restrict__ w_b,
                                                   const float* __restrict__ w_s,
                                                   const float* __restrict__ grid,
                                                   unsigned short* __restrict__ A,
                                                   unsigned short* __restrict__ B) {
    int blk = blockIdx.x;
    int tid = threadIdx.x;
    if (blk < 512) {
        int e = (blk * 256 + tid) * 8;       // element base in x (row-aligned)
        float g0 = grid[0];
        float dl = grid[1] - g0;             // uniform spacing (4/7)
        float d2 = dl * dl;
        float dn[NG];
#pragma unroll
        for (int n = 0; n < NG; ++n) dn[n] = __expf(-d2 * (float)(n * n));
        float4 x0 = *(const float4*)&x[e];
        float4 x1 = *(const float4*)&x[e + 4];
        float xv[8] = {x0.x, x0.y, x0.z, x0.w, x1.x, x1.y, x1.z, x1.w};
        unsigned short sv[8], lv[8];
#pragma unroll
        for (int j = 0; j < 8; ++j) {
            float u  = xv[j] - g0;
            float e1 = __expf(-u * u);
            float q  = __expf(2.f * dl * u);
            float p  = dn[NG - 1];
#pragma unroll
            for (int n = NG - 2; n >= 0; --n) p = p * q + dn[n];
            sv[j] = f2bf(e1 * p);
            lv[j] = f2bf(xv[j] / (1.f + __expf(-xv[j])));
        }
        int b = e >> 9, i = e & 511;
        *(int4*)&A[b * KTOT + i]       = *(int4*)sv;
        *(int4*)&A[b * KTOT + 512 + i] = *(int4*)lv;
    } else {
        int e = ((blk - 512) * 256 + tid) * 8;
        float acc[8] = {};
#pragma unroll
        for (int a = 0; a < NG; ++a) {
            float4 c0 = *(const float4*)&c[(size_t)a * (OUT * IN) + e];
            float4 c1 = *(const float4*)&c[(size_t)a * (OUT * IN) + e + 4];
            acc[0] += c0.x; acc[1] += c0.y; acc[2] += c0.z; acc[3] += c0.w;
            acc[4] += c1.x; acc[5] += c1.y; acc[6] += c1.z; acc[7] += c1.w;
        }
        float4 s0 = *(const float4*)&w_s[e];
        float4 s1 = *(const float4*)&w_s[e + 4];
        float sw[8] = {s0.x, s0.y, s0.z, s0.w, s1.x, s1.y, s1.z, s1.w};
        float4 b0 = *(const float4*)&w_b[e];
        float4 b1 = *(const float4*)&w_b[e + 4];
        float bw[8] = {b0.x, b0.y, b0.z, b0.w, b1.x, b1.y, b1.z, b1.w};
        unsigned short cv[8], bv[8];
#pragma unroll
        for (int j = 0; j < 8; ++j) { cv[j] = f2bf(acc[j] * sw[j]); bv[j] = f2bf(bw[j]); }
        int o = e >> 9, i = e & 511;
        *(int4*)&B[o * KTOT + i]       = *(int4*)cv;
        *(int4*)&B[o * KTOT + 512 + i] = *(int4*)bv;
    }
}

// ---------------------------------------------------------------------------
// bf16 MFMA GEMM (round-4 verbatim): out = A'[2048][1024] * B'[512][1024]^T
// 64x64 tile, 512 threads = 8 waves (each 16x32), BK=64, double-buffered LDS,
// 2-deep reg prefetch, 256 blocks (1/CU), XCD-aware decode.
// ---------------------------------------------------------------------------
__global__ __launch_bounds__(512) void gemm_kernel(const unsigned short* __restrict__ A,
                                                   const unsigned short* __restrict__ B,
                                                   float* __restrict__ outp) {
    __shared__ short As[2][BM * PAD];
    __shared__ short Bs[2][BN * PAD];

    int tid  = threadIdx.x;
    int lane = tid & 63;
    int w    = tid >> 6;               // 0..7
    int wm   = w >> 1, wn = w & 1;     // 4x2 wave grid over 64x64 tile
    int lr   = lane & 15, lg = lane >> 4;

    int bid  = blockIdx.x;
    int mg   = bid & 7;
    int rest = bid >> 3;
    int sub  = rest >> 3;              // 0..3
    int ncol = rest & 7;               // 0..7
    int m0   = (mg * 4 + sub) * BM;
    int n0   = ncol * BN;

    int srow = tid >> 3;   // 0..63
    int sc8  = tid & 7;

    const int4* Ag = (const int4*)&A[(size_t)(m0 + srow) * KTOT + sc8 * 8];
    const int4* Bg = (const int4*)&B[(size_t)(n0 + srow) * KTOT + sc8 * 8];

    int wo = srow * PAD + sc8 * 8;

    f32x4 acc0 = {0.f, 0.f, 0.f, 0.f};
    f32x4 acc1 = {0.f, 0.f, 0.f, 0.f};

    int4 ca = Ag[0], cb = Bg[0];
    *(int4*)&As[0][wo] = ca;
    *(int4*)&Bs[0][wo] = cb;
    ca = Ag[8]; cb = Bg[8];
    __syncthreads();

#pragma unroll
    for (int it = 0; it < NIT; ++it) {
        int cur = it & 1;
        if (it + 1 < NIT) {
            *(int4*)&As[cur ^ 1][wo] = ca;
            *(int4*)&Bs[cur ^ 1][wo] = cb;
            if (it + 2 < NIT) { ca = Ag[(it + 2) * 8]; cb = Bg[(it + 2) * 8]; }
        }
#pragma unroll
        for (int ks = 0; ks < 2; ++ks) {
            bf16x8 a  = *(const bf16x8*)&As[cur][(wm * 16 + lr)      * PAD + ks * 32 + lg * 8];
            bf16x8 b0 = *(const bf16x8*)&Bs[cur][(wn * 32 + lr)      * PAD + ks * 32 + lg * 8];
            bf16x8 b1 = *(const bf16x8*)&Bs[cur][(wn * 32 + 16 + lr) * PAD + ks * 32 + lg * 8];
            acc0 = __builtin_amdgcn_mfma_f32_16x16x32_bf16(a, b0, acc0, 0, 0, 0);
            acc1 = __builtin_amdgcn_mfma_f32_16x16x32_bf16(a, b1, acc1, 0, 0, 0);
        }
        __syncthreads();
    }

    // C/D layout: col = lane&15, row = (lane>>4)*4 + reg   [measured m89/m91]
    int orow = m0 + wm * 16 + lg * 4;
    int ocol = n0 + wn * 32 + lr;
#pragma unroll
    for (int r = 0; r < 4; ++r) {
        outp[(size_t)(orow + r) * OUT + ocol]      = acc0[r];
        outp[(size_t)(orow + r) * OUT + ocol + 16] = acc1[r];
    }
}

extern "C" void kernel_launch(void* const* d_in, const int* in_sizes, int n_in,
                              void* d_out, int out_size, void* d_ws, size_t ws_size,
                              hipStream_t stream) {
    (void)in_sizes; (void)n_in; (void)out_size; (void)ws_size;
    const float* x    = (const float*)d_in[0];
    const float* c    = (const float*)d_in[1];
    const float* w_b  = (const float*)d_in[2];
    const float* w_s  = (const float*)d_in[3];
    const float* grid = (const float*)d_in[4];
    float* outp = (float*)d_out;

    unsigned short* A = (unsigned short*)d_ws;             // 2048x1024 bf16 = 4 MiB
    unsigned short* B = A + (size_t)BATCH * KTOT;          // 512x1024 bf16 = 1 MiB

    prep_kernel<<<512 + 128, 256, 0, stream>>>(x, c, w_b, w_s, grid, A, B);
    // Launch gemm 3x (idempotent; identical output). dT vs round-4 baseline
    // isolates the gemm's (warm) duration: dT = 2*(gemm_warm + launch).
    gemm_kernel<<<256, 512, 0, stream>>>(A, B, outp);
    gemm_kernel<<<256, 512, 0, stream>>>(A, B, outp);
    gemm_kernel<<<256, 512, 0, stream>>>(A, B, outp);
}